// Round 7
// baseline (563.477 us; speedup 1.0000x reference)
//
#include <hip/hip_runtime.h>

typedef short v8s __attribute__((ext_vector_type(8)));
typedef float v4f __attribute__((ext_vector_type(4)));

// ---- problem constants ----
#define L_SEQ  2048
#define DPROJ  8352
#define CONVD  4224
#define DIN    4096
#define NH     32
#define HD     128
#define NSTATE 64
#define NCHUNK 8
#define CKLEN  256

#define GLOAD_LDS16(gp, lp) \
  __builtin_amdgcn_global_load_lds((const __attribute__((address_space(1))) void*)(gp), \
                                   (__attribute__((address_space(3))) void*)(lp), 16, 0, 0)

__device__ __forceinline__ unsigned short to_bf16(float f) {
  unsigned u = __float_as_uint(f);
  return (unsigned short)((u + 0x7fffu + ((u >> 16) & 1u)) >> 16);
}

// ---------------- fp32 -> bf16 cast, 8 elts/thread ----------------
__global__ void cvt_bf16_kernel(const float* __restrict__ in,
                                unsigned short* __restrict__ out, int n) {
  int i = (blockIdx.x * 256 + threadIdx.x) * 8;
  if (i + 8 <= n) {
    float4 a = *(const float4*)(in + i);
    float4 b = *(const float4*)(in + i + 4);
    v8s r;
    r[0] = (short)to_bf16(a.x); r[1] = (short)to_bf16(a.y);
    r[2] = (short)to_bf16(a.z); r[3] = (short)to_bf16(a.w);
    r[4] = (short)to_bf16(b.x); r[5] = (short)to_bf16(b.y);
    r[6] = (short)to_bf16(b.z); r[7] = (short)to_bf16(b.w);
    *(v8s*)(out + i) = r;
  }
}

// ---------------- bf16 NT GEMM 128x128 ----------------
__global__ __launch_bounds__(256) void gemm_nt_bf16(
    const unsigned short* __restrict__ A, const unsigned short* __restrict__ B,
    float* __restrict__ C, int M, int N, int K)
{
  __shared__ unsigned short As[128 * 32];
  __shared__ unsigned short Bs[128 * 32];
  const int m0 = blockIdx.x * 128;
  const int n0 = blockIdx.y * 128;
  const int tid = threadIdx.x;
  const int wave = tid >> 6, lane = tid & 63;
  const int wm = (wave & 1) * 64, wn = (wave >> 1) * 64;
  const int lrow = lane & 15, lquad = lane >> 4;

  v4f acc[4][4] = {};

  for (int k0 = 0; k0 < K; k0 += 32) {
    __syncthreads();
#pragma unroll
    for (int r = 0; r < 2; ++r) {
      int e = wave * 128 + r * 64 + lane;
      int row = e >> 2;
      int kq = (e & 3) * 8;
      const unsigned short* ap = A + (size_t)(m0 + row) * K + k0 + kq;
      GLOAD_LDS16(ap, As + wave * 1024 + r * 512);
      int br = n0 + row; if (br >= N) br = N - 1;
      const unsigned short* bp = B + (size_t)br * K + k0 + kq;
      GLOAD_LDS16(bp, Bs + wave * 1024 + r * 512);
    }
    __syncthreads();
    v8s af[4], bfr[4];
#pragma unroll
    for (int i = 0; i < 4; ++i)
      af[i] = *(const v8s*)&As[(wm + i * 16 + lrow) * 32 + lquad * 8];
#pragma unroll
    for (int j = 0; j < 4; ++j)
      bfr[j] = *(const v8s*)&Bs[(wn + j * 16 + lrow) * 32 + lquad * 8];
#pragma unroll
    for (int i = 0; i < 4; ++i)
#pragma unroll
      for (int j = 0; j < 4; ++j)
        acc[i][j] = __builtin_amdgcn_mfma_f32_16x16x32_bf16(af[i], bfr[j], acc[i][j], 0, 0, 0);
  }

#pragma unroll
  for (int i = 0; i < 4; ++i) {
    int grow = m0 + wm + i * 16 + lquad * 4;
#pragma unroll
    for (int j = 0; j < 4; ++j) {
      int gcol = n0 + wn + j * 16 + lrow;
      if (gcol < N) {
#pragma unroll
        for (int r = 0; r < 4; ++r)
          C[(size_t)(grow + r) * N + gcol] = acc[i][j][r];
      }
    }
  }
}

// ---------------- bf16 NT GEMM 64x128 ----------------
__global__ __launch_bounds__(256) void gemm_nt_bf16_64(
    const unsigned short* __restrict__ A, const unsigned short* __restrict__ B,
    float* __restrict__ C, int M, int N, int K)
{
  __shared__ unsigned short As[64 * 32];
  __shared__ unsigned short Bs[128 * 32];
  const int m0 = blockIdx.x * 64;
  const int n0 = blockIdx.y * 128;
  const int tid = threadIdx.x;
  const int wave = tid >> 6, lane = tid & 63;
  const int wm = (wave & 1) * 32, wn = (wave >> 1) * 64;
  const int lrow = lane & 15, lquad = lane >> 4;

  v4f acc[2][4] = {};

  for (int k0 = 0; k0 < K; k0 += 32) {
    __syncthreads();
    {
      int e = wave * 64 + lane;
      int row = e >> 2;
      int kq = (e & 3) * 8;
      const unsigned short* ap = A + (size_t)(m0 + row) * K + k0 + kq;
      GLOAD_LDS16(ap, As + wave * 512);
    }
#pragma unroll
    for (int r = 0; r < 2; ++r) {
      int e = wave * 128 + r * 64 + lane;
      int row = e >> 2;
      int kq = (e & 3) * 8;
      const unsigned short* bp = B + (size_t)(n0 + row) * K + k0 + kq;
      GLOAD_LDS16(bp, Bs + wave * 1024 + r * 512);
    }
    __syncthreads();
    v8s af[2], bfr[4];
#pragma unroll
    for (int i = 0; i < 2; ++i)
      af[i] = *(const v8s*)&As[(wm + i * 16 + lrow) * 32 + lquad * 8];
#pragma unroll
    for (int j = 0; j < 4; ++j)
      bfr[j] = *(const v8s*)&Bs[(wn + j * 16 + lrow) * 32 + lquad * 8];
#pragma unroll
    for (int i = 0; i < 2; ++i)
#pragma unroll
      for (int j = 0; j < 4; ++j)
        acc[i][j] = __builtin_amdgcn_mfma_f32_16x16x32_bf16(af[i], bfr[j], acc[i][j], 0, 0, 0);
  }

#pragma unroll
  for (int i = 0; i < 2; ++i) {
    int grow = m0 + wm + i * 16 + lquad * 4;
#pragma unroll
    for (int j = 0; j < 4; ++j) {
      int gcol = n0 + wn + j * 16 + lrow;
#pragma unroll
      for (int r = 0; r < 4; ++r)
        C[(size_t)(grow + r) * N + gcol] = acc[i][j][r];
    }
  }
}

// ---------------- causal depthwise conv1d(4) + SiLU ----------------
__global__ void conv_silu_kernel(const float* __restrict__ zx,
                                 const float* __restrict__ cw,
                                 const float* __restrict__ cb,
                                 float* __restrict__ out)
{
  int e = blockIdx.x * 256 + threadIdx.x;
  int l = e / CONVD, c = e % CONVD;
  float acc = cb[c];
#pragma unroll
  for (int j = 0; j < 4; ++j) {
    int ls = l - 3 + j;
    if (ls >= 0) acc += zx[(size_t)ls * DPROJ + DIN + c] * cw[c * 4 + j];
  }
  out[e] = acc / (1.f + __expf(-acc));
}

// ---------------- dt = softplus(raw + bias) ----------------
__global__ void dt_kernel(const float* __restrict__ zx,
                          const float* __restrict__ dtb,
                          float* __restrict__ dt)
{
  int e = blockIdx.x * 256 + threadIdx.x;
  int l = e >> 5, h = e & 31;
  float v = zx[(size_t)l * DPROJ + (DPROJ - NH) + h] + dtb[h];
  dt[e] = (v > 20.f) ? v : log1pf(__expf(v));
}

// ---------------- per-(head,chunk) inclusive cumsum of A*dt ----------------
__global__ void acum_kernel(const float* __restrict__ dt,
                            const float* __restrict__ alog,
                            float* __restrict__ acum)
{
  int h = blockIdx.x & 31, c = blockIdx.x >> 5;
  int t = threadIdx.x;
  int l = c * CKLEN + t;
  float A = -__expf(alog[h]);
  __shared__ float s[256];
  s[t] = A * dt[l * NH + h];
  __syncthreads();
  for (int off = 1; off < 256; off <<= 1) {
    float add = (t >= off) ? s[t - off] : 0.f;
    __syncthreads();
    s[t] += add;
    __syncthreads();
  }
  acum[h * L_SEQ + l] = s[t];
}

// ---------------- prep: Xd (bf16 [c][h][p][t]), Btw (bf16 [c][h][n][t]),
//                  Cbf (bf16 [c][l][n], head-independent, NO exp) ----------
__global__ __launch_bounds__(256) void prep_kernel(
    const float* __restrict__ xbc, const float* __restrict__ dt,
    const float* __restrict__ acum, unsigned short* __restrict__ Xd,
    unsigned short* __restrict__ Btw, unsigned short* __restrict__ Cbf)
{
  const int h = blockIdx.x & 31, c = blockIdx.x >> 5;
  const int tid = threadIdx.x;
  __shared__ float Ac[256], Dt[256], Wd[256];
  __shared__ float Xs[32][129];
  __shared__ float Bs2[32][65];
  int l = c * CKLEN + tid;
  float a = acum[h * L_SEQ + l];
  Ac[tid] = a;
  Dt[tid] = dt[l * NH + h];
  __syncthreads();
  float alast = Ac[255];
  Wd[tid] = __expf(fminf(alast - a, 0.f));
  __syncthreads();
  unsigned short* XdB = Xd + (size_t)(c * NH + h) * (HD * CKLEN);
  unsigned short* BtB = Btw + (size_t)(c * NH + h) * (NSTATE * CKLEN);
  for (int t0 = 0; t0 < CKLEN; t0 += 32) {
    for (int e = tid; e < 32 * 128; e += 256) {
      int tt = e >> 7, pp = e & 127;
      Xs[tt][pp] = xbc[(size_t)(c * CKLEN + t0 + tt) * CONVD + h * HD + pp];
    }
    for (int e = tid; e < 32 * 64; e += 256) {
      int tt = e >> 6, nn = e & 63;
      Bs2[tt][nn] = xbc[(size_t)(c * CKLEN + t0 + tt) * CONVD + DIN + nn];
    }
    __syncthreads();
    {
      int p = tid >> 1, th = (tid & 1) * 16;
      v8s r0, r1;
#pragma unroll
      for (int k = 0; k < 8; ++k) {
        r0[k] = (short)to_bf16(Xs[th + k][p] * Dt[t0 + th + k]);
        r1[k] = (short)to_bf16(Xs[th + 8 + k][p] * Dt[t0 + th + 8 + k]);
      }
      *(v8s*)&XdB[p * CKLEN + t0 + th] = r0;
      *(v8s*)&XdB[p * CKLEN + t0 + th + 8] = r1;
    }
    {
      int n = tid >> 2, tq = (tid & 3) * 8;
      v8s r;
#pragma unroll
      for (int k = 0; k < 8; ++k)
        r[k] = (short)to_bf16(Bs2[tq + k][n] * Wd[t0 + tq + k]);
      *(v8s*)&BtB[n * CKLEN + t0 + tq] = r;
    }
    __syncthreads();
  }
  if (h == 0) {
    for (int e = tid; e < CKLEN * NSTATE; e += 256) {
      int ll = e >> 6, nn = e & 63;
      Cbf[(size_t)c * (CKLEN * NSTATE) + e] =
          to_bf16(xbc[(size_t)(c * CKLEN + ll) * CONVD + DIN + NSTATE + nn]);
    }
  }
}

// ---------------- G[c][l][s] = C_l . B_s (fp32, per chunk) ----------------
__global__ __launch_bounds__(256) void g_kernel(const float* __restrict__ xbc,
                                                float* __restrict__ G)
{
  int c = blockIdx.z;
  int l0 = blockIdx.y * 64, s0 = blockIdx.x * 64;
  __shared__ float Cs[64][65];
  __shared__ float Bs[64][65];
  int tid = threadIdx.x;
  for (int e = tid; e < 64 * 64; e += 256) {
    int r = e >> 6, k = e & 63;
    Cs[r][k] = xbc[(size_t)(c * CKLEN + l0 + r) * CONVD + DIN + NSTATE + k];
    Bs[r][k] = xbc[(size_t)(c * CKLEN + s0 + r) * CONVD + DIN + k];
  }
  __syncthreads();
  int tx = tid & 15, ty = tid >> 4;
  float acc[4][4] = {};
  for (int k = 0; k < 64; ++k) {
    float a[4], b[4];
#pragma unroll
    for (int i = 0; i < 4; ++i) a[i] = Cs[ty * 4 + i][k];
#pragma unroll
    for (int j = 0; j < 4; ++j) b[j] = Bs[tx * 4 + j][k];
#pragma unroll
    for (int i = 0; i < 4; ++i)
#pragma unroll
      for (int j = 0; j < 4; ++j) acc[i][j] += a[i] * b[j];
  }
  for (int i = 0; i < 4; ++i)
    for (int j = 0; j < 4; ++j)
      G[((size_t)c * CKLEN + l0 + ty * 4 + i) * CKLEN + s0 + tx * 4 + j] = acc[i][j];
}

// ---------------- Gexp[c][h][l][s] = masked G * exp(Ac[l]-Ac[s]) bf16 -----
__global__ __launch_bounds__(256) void gexp_kernel(
    const float* __restrict__ G, const float* __restrict__ acum,
    unsigned short* __restrict__ Gexp)
{
  const int h = blockIdx.x & 31, c = blockIdx.x >> 5;
  const int tid = threadIdx.x;
  __shared__ float Ac[256];
  Ac[tid] = acum[h * L_SEQ + c * CKLEN + tid];
  __syncthreads();
  const float* Gc = G + (size_t)c * (CKLEN * CKLEN);
  unsigned short* Go = Gexp + (size_t)(c * NH + h) * (CKLEN * CKLEN);
  for (int i = 0; i < 256; ++i) {
    int e = i * 256 + tid;    // l = i, s = tid
    float m = 0.f;
    if (tid <= i) m = Gc[e] * __expf(fminf(Ac[i] - Ac[tid], 0.f));
    Go[e] = to_bf16(m);
  }
}

// ---------------- chunk states: st[p][n] = Xd[p][:] . Btw[n][:] -----------
__global__ __launch_bounds__(256) void states_kernel_v2(
    const unsigned short* __restrict__ Xd, const unsigned short* __restrict__ Btw,
    float* __restrict__ st)
{
  const int h = blockIdx.x & 31, c = blockIdx.x >> 5;
  const int tid = threadIdx.x;
  const int wave = tid >> 6, lane = tid & 63;
  const int wm = (wave & 1) * 64, wn = (wave >> 1) * 32;
  const int lrow = lane & 15, lquad = lane >> 4;

  __shared__ unsigned short As[128 * 32];
  __shared__ unsigned short Bs[64 * 32];
  const unsigned short* Ab = Xd + (size_t)(c * NH + h) * (HD * CKLEN);
  const unsigned short* Bb = Btw + (size_t)(c * NH + h) * (NSTATE * CKLEN);

  v4f acc[4][2] = {};

  for (int k0 = 0; k0 < CKLEN; k0 += 32) {
    __syncthreads();
#pragma unroll
    for (int r = 0; r < 2; ++r) {
      int e = wave * 128 + r * 64 + lane;
      int row = e >> 2, kq = (e & 3) * 8;
      GLOAD_LDS16(Ab + (size_t)row * CKLEN + k0 + kq, As + wave * 1024 + r * 512);
    }
    {
      int e = wave * 64 + lane;
      int row = e >> 2, kq = (e & 3) * 8;
      GLOAD_LDS16(Bb + (size_t)row * CKLEN + k0 + kq, Bs + wave * 512);
    }
    __syncthreads();
    v8s af[4], bfr[2];
#pragma unroll
    for (int i = 0; i < 4; ++i)
      af[i] = *(const v8s*)&As[(wm + i * 16 + lrow) * 32 + lquad * 8];
#pragma unroll
    for (int j = 0; j < 2; ++j)
      bfr[j] = *(const v8s*)&Bs[(wn + j * 16 + lrow) * 32 + lquad * 8];
#pragma unroll
    for (int i = 0; i < 4; ++i)
#pragma unroll
      for (int j = 0; j < 2; ++j)
        acc[i][j] = __builtin_amdgcn_mfma_f32_16x16x32_bf16(af[i], bfr[j], acc[i][j], 0, 0, 0);
  }

  float* outp = st + (size_t)(c * NH + h) * (HD * NSTATE);
#pragma unroll
  for (int i = 0; i < 4; ++i) {
    int p0 = wm + i * 16 + lquad * 4;
#pragma unroll
    for (int j = 0; j < 2; ++j) {
      int n = wn + j * 16 + lrow;
#pragma unroll
      for (int r = 0; r < 4; ++r)
        outp[(size_t)(p0 + r) * NSTATE + n] = acc[i][j][r];
    }
  }
}

// ---------------- inter-chunk scan -> bf16 sp ----------------
__global__ void scan_kernel(const float* __restrict__ acum,
                            const float* __restrict__ st,
                            unsigned short* __restrict__ spbf)
{
  int e = blockIdx.x * 256 + threadIdx.x;   // over NH*HD*NSTATE = 262144
  int h = e >> 13;
  float running = 0.f;
#pragma unroll
  for (int c = 0; c < NCHUNK; ++c) {
    spbf[(size_t)c * 262144 + e] = to_bf16(running);
    float dec = __expf(fminf(acum[h * L_SEQ + c * CKLEN + 255], 0.f));
    running = running * dec + st[(size_t)c * 262144 + e];
  }
}

// ---------------- Y: acc = Cbf @ sp^T; acc *= exp(Ac[l]); acc += Gexp @ Xd^T;
//                  Y = acc + D*xs  (state-first so the head-dependent exp is a
//                  row-scale of the fp32 accumulator — no per-head Cexp)
__global__ __launch_bounds__(256) void y_kernel_v2(
    const unsigned short* __restrict__ Gexp, const unsigned short* __restrict__ Xd,
    const unsigned short* __restrict__ Cbf, const unsigned short* __restrict__ spbf,
    const float* __restrict__ xbc, const float* __restrict__ acum,
    const float* __restrict__ Dp, float* __restrict__ Y)
{
  const int b = blockIdx.x, h = blockIdx.y, c = blockIdx.z;
  const int tid = threadIdx.x;
  const int wave = tid >> 6, lane = tid & 63;
  const int wm = wave * 32;
  const int lrow = lane & 15, lquad = lane >> 4;

  __shared__ unsigned short As[128 * 32];
  __shared__ unsigned short Bs[128 * 32];

  v4f acc[2][8] = {};

  // ---- state part first: acc = Cbf @ sp^T (head-independent A operand) ----
  const unsigned short* Ca = Cbf + (size_t)c * (CKLEN * NSTATE) + (size_t)b * 128 * NSTATE;
  const unsigned short* Sb = spbf + (size_t)(c * NH + h) * (HD * NSTATE);
  for (int n0 = 0; n0 < NSTATE; n0 += 32) {
    __syncthreads();
#pragma unroll
    for (int r = 0; r < 2; ++r) {
      int e = wave * 128 + r * 64 + lane;
      int row = e >> 2, kq = (e & 3) * 8;
      GLOAD_LDS16(Ca + (size_t)row * NSTATE + n0 + kq, As + wave * 1024 + r * 512);
      GLOAD_LDS16(Sb + (size_t)row * NSTATE + n0 + kq, Bs + wave * 1024 + r * 512);
    }
    __syncthreads();
    v8s af[2], bfr[8];
#pragma unroll
    for (int i = 0; i < 2; ++i)
      af[i] = *(const v8s*)&As[(wm + i * 16 + lrow) * 32 + lquad * 8];
#pragma unroll
    for (int j = 0; j < 8; ++j)
      bfr[j] = *(const v8s*)&Bs[(j * 16 + lrow) * 32 + lquad * 8];
#pragma unroll
    for (int i = 0; i < 2; ++i)
#pragma unroll
      for (int j = 0; j < 8; ++j)
        acc[i][j] = __builtin_amdgcn_mfma_f32_16x16x32_bf16(af[i], bfr[j], acc[i][j], 0, 0, 0);
  }

  // ---- row-scale by per-head decay exp(Ac[l]) (fp32, exact) ----
#pragma unroll
  for (int i = 0; i < 2; ++i) {
#pragma unroll
    for (int r = 0; r < 4; ++r) {
      int Lg = c * CKLEN + b * 128 + wm + i * 16 + lquad * 4 + r;
      float eA = __expf(fminf(acum[h * L_SEQ + Lg], 0.f));
#pragma unroll
      for (int j = 0; j < 8; ++j) acc[i][j][r] *= eA;
    }
  }

  // ---- diagonal part: acc += Gexp @ Xd^T ----
  const unsigned short* Ga = Gexp + (size_t)(c * NH + h) * (CKLEN * CKLEN)
                           + (size_t)b * 128 * CKLEN;
  const unsigned short* Xb = Xd + (size_t)(c * NH + h) * (HD * CKLEN);

  const int smax = (b + 1) * 128;
  for (int s0 = 0; s0 < smax; s0 += 32) {
    __syncthreads();
#pragma unroll
    for (int r = 0; r < 2; ++r) {
      int e = wave * 128 + r * 64 + lane;
      int row = e >> 2, kq = (e & 3) * 8;
      GLOAD_LDS16(Ga + (size_t)row * CKLEN + s0 + kq, As + wave * 1024 + r * 512);
      GLOAD_LDS16(Xb + (size_t)row * CKLEN + s0 + kq, Bs + wave * 1024 + r * 512);
    }
    __syncthreads();
    if (s0 <= b * 128 + wm + 31) {    // causal wave skip (Gexp upper part = 0)
      v8s af[2], bfr[8];
#pragma unroll
      for (int i = 0; i < 2; ++i)
        af[i] = *(const v8s*)&As[(wm + i * 16 + lrow) * 32 + lquad * 8];
#pragma unroll
      for (int j = 0; j < 8; ++j)
        bfr[j] = *(const v8s*)&Bs[(j * 16 + lrow) * 32 + lquad * 8];
#pragma unroll
      for (int i = 0; i < 2; ++i)
#pragma unroll
        for (int j = 0; j < 8; ++j)
          acc[i][j] = __builtin_amdgcn_mfma_f32_16x16x32_bf16(af[i], bfr[j], acc[i][j], 0, 0, 0);
    }
  }

  const float Dh = Dp[h];
#pragma unroll
  for (int i = 0; i < 2; ++i) {
#pragma unroll
    for (int j = 0; j < 8; ++j) {
      int p = j * 16 + lrow;
#pragma unroll
      for (int r = 0; r < 4; ++r) {
        int Lg = c * CKLEN + b * 128 + wm + i * 16 + lquad * 4 + r;
        float xs = xbc[(size_t)Lg * CONVD + h * HD + p];
        Y[(size_t)Lg * DIN + h * HD + p] = acc[i][j][r] + Dh * xs;
      }
    }
  }
}

// ---------------- gated RMSNorm -> bf16 ----------------
__global__ __launch_bounds__(256) void norm_gate_kernel(const float* __restrict__ Y,
                                                        const float* __restrict__ zx,
                                                        const float* __restrict__ nw,
                                                        unsigned short* __restrict__ gbf)
{
  int l = blockIdx.x;
  int t = threadIdx.x;
  float g[16];
  float ss = 0.f;
#pragma unroll
  for (int i = 0; i < 16; ++i) {
    int idx = i * 256 + t;
    float z = zx[(size_t)l * DPROJ + idx];
    float y = Y[(size_t)l * DIN + idx];
    float gv = y * (z / (1.f + __expf(-z)));
    g[i] = gv;
    ss += gv * gv;
  }
#pragma unroll
  for (int off = 32; off > 0; off >>= 1) ss += __shfl_down(ss, off);
  __shared__ float red[4];
  if ((t & 63) == 0) red[t >> 6] = ss;
  __syncthreads();
  float total = red[0] + red[1] + red[2] + red[3];
  float scale = rsqrtf(total / (float)DIN + 1e-5f);
#pragma unroll
  for (int i = 0; i < 16; ++i) {
    int idx = i * 256 + t;
    gbf[(size_t)l * DIN + idx] = to_bf16(g[i] * scale * nw[idx]);
  }
}

// ---------------- launch ----------------
extern "C" void kernel_launch(void* const* d_in, const int* in_sizes, int n_in,
                              void* d_out, int out_size, void* d_ws, size_t ws_size,
                              hipStream_t stream) {
  const float* x    = (const float*)d_in[0];
  const float* w1   = (const float*)d_in[1];
  const float* cw   = (const float*)d_in[2];
  const float* cb   = (const float*)d_in[3];
  const float* dtb  = (const float*)d_in[4];
  const float* alog = (const float*)d_in[5];
  const float* Dp   = (const float*)d_in[6];
  const float* nw   = (const float*)d_in[7];
  const float* w2   = (const float*)d_in[8];
  float* out = (float*)d_out;
  float* ws  = (float*)d_ws;

  // scratch layout (float units). Gexp/Btw overlay xbf/w1bf (dead after gemm1).
  unsigned short* xbf  = (unsigned short*)(ws + 0);          // 2048*2048 bf16
  unsigned short* w1bf = (unsigned short*)(ws + 2097152);    // 8352*2048 bf16
  unsigned short* Gexp = (unsigned short*)(ws + 0);          // 8*32*256*256 bf16 (post-gemm1)
  unsigned short* Btw  = (unsigned short*)(ws + 8388608);    // 8*32*64*256 bf16 (post-gemm1)
  unsigned short* w2bf = (unsigned short*)(ws + 10649600);   // 2048*4096 bf16
  float* zx   = ws + 14843904;   // 2048*8352
  float* xbc  = ws + 31948800;   // 2048*4224
  float* dt   = ws + 40599552;   // 2048*32
  float* acum = ws + 40665088;   // 32*2048
  float* G    = ws + 40730624;   // 8*256*256 fp32
  float* st   = ws + 41254912;   // 8*32*128*64 fp32
  float* Y    = ws + 43352064;   // 2048*4096
  unsigned short* gbf  = (unsigned short*)(ws + 51740672);   // 2048*4096 bf16
  unsigned short* Xd   = (unsigned short*)(ws + 53837824);   // 8*32*128*256 bf16
  unsigned short* Cbf  = (unsigned short*)(ws + 58032128);   // 8*256*64 bf16
  unsigned short* spbf = (unsigned short*)(ws + 58097664);   // 8*32*128*64 bf16

  cvt_bf16_kernel<<<4194304 / 2048, 256, 0, stream>>>(x, xbf, 4194304);
  cvt_bf16_kernel<<<17104896 / 2048, 256, 0, stream>>>(w1, w1bf, 17104896);
  cvt_bf16_kernel<<<8388608 / 2048, 256, 0, stream>>>(w2, w2bf, 8388608);

  // zxbcdt = x @ in_proj_w^T   (M=2048, N=8352, K=2048)
  gemm_nt_bf16<<<dim3(16, 66), 256, 0, stream>>>(xbf, w1bf, zx, 2048, 8352, 2048);

  conv_silu_kernel<<<(L_SEQ * CONVD) / 256, 256, 0, stream>>>(zx, cw, cb, xbc);
  dt_kernel<<<(L_SEQ * NH) / 256, 256, 0, stream>>>(zx, dtb, dt);
  acum_kernel<<<NCHUNK * NH, 256, 0, stream>>>(dt, alog, acum);

  prep_kernel<<<NCHUNK * NH, 256, 0, stream>>>(xbc, dt, acum, Xd, Btw, Cbf);
  g_kernel<<<dim3(4, 4, NCHUNK), 256, 0, stream>>>(xbc, G);
  gexp_kernel<<<NCHUNK * NH, 256, 0, stream>>>(G, acum, Gexp);

  states_kernel_v2<<<NCHUNK * NH, 256, 0, stream>>>(Xd, Btw, st);
  scan_kernel<<<262144 / 256, 256, 0, stream>>>(acum, st, spbf);
  y_kernel_v2<<<dim3(2, NH, NCHUNK), 256, 0, stream>>>(Gexp, Xd, Cbf, spbf, xbc, acum, Dp, Y);

  norm_gate_kernel<<<L_SEQ, 256, 0, stream>>>(Y, zx, nw, gbf);

  // out = g @ out_proj_w^T   (M=2048, N=2048, K=4096)
  gemm_nt_bf16_64<<<dim3(32, 16), 256, 0, stream>>>(gbf, w2bf, out, 2048, 2048, 4096);
}

// Round 8
// 494.044 us; speedup vs baseline: 1.1405x; 1.1405x over previous
//
#include <hip/hip_runtime.h>

typedef short v8s __attribute__((ext_vector_type(8)));
typedef float v4f __attribute__((ext_vector_type(4)));

// ---- problem constants ----
#define L_SEQ  2048
#define DPROJ  8352
#define CONVD  4224
#define DIN    4096
#define NH     32
#define HD     128
#define NSTATE 64
#define NCHUNK 8
#define CKLEN  256

#define GLOAD_LDS16(gp, lp) \
  __builtin_amdgcn_global_load_lds((const __attribute__((address_space(1))) void*)(gp), \
                                   (__attribute__((address_space(3))) void*)(lp), 16, 0, 0)

__device__ __forceinline__ unsigned short to_bf16(float f) {
  unsigned u = __float_as_uint(f);
  return (unsigned short)((u + 0x7fffu + ((u >> 16) & 1u)) >> 16);
}

// ---------------- fp32 -> bf16 cast, 8 elts/thread ----------------
__global__ void cvt_bf16_kernel(const float* __restrict__ in,
                                unsigned short* __restrict__ out, int n) {
  int i = (blockIdx.x * 256 + threadIdx.x) * 8;
  if (i + 8 <= n) {
    float4 a = *(const float4*)(in + i);
    float4 b = *(const float4*)(in + i + 4);
    v8s r;
    r[0] = (short)to_bf16(a.x); r[1] = (short)to_bf16(a.y);
    r[2] = (short)to_bf16(a.z); r[3] = (short)to_bf16(a.w);
    r[4] = (short)to_bf16(b.x); r[5] = (short)to_bf16(b.y);
    r[6] = (short)to_bf16(b.z); r[7] = (short)to_bf16(b.w);
    *(v8s*)(out + i) = r;
  }
}

// ---------------- bf16 NT GEMM 128x128 ----------------
__global__ __launch_bounds__(256) void gemm_nt_bf16(
    const unsigned short* __restrict__ A, const unsigned short* __restrict__ B,
    float* __restrict__ C, int M, int N, int K)
{
  __shared__ unsigned short As[128 * 32];
  __shared__ unsigned short Bs[128 * 32];
  const int m0 = blockIdx.x * 128;
  const int n0 = blockIdx.y * 128;
  const int tid = threadIdx.x;
  const int wave = tid >> 6, lane = tid & 63;
  const int wm = (wave & 1) * 64, wn = (wave >> 1) * 64;
  const int lrow = lane & 15, lquad = lane >> 4;

  v4f acc[4][4] = {};

  for (int k0 = 0; k0 < K; k0 += 32) {
    __syncthreads();
#pragma unroll
    for (int r = 0; r < 2; ++r) {
      int e = wave * 128 + r * 64 + lane;
      int row = e >> 2;
      int kq = (e & 3) * 8;
      const unsigned short* ap = A + (size_t)(m0 + row) * K + k0 + kq;
      GLOAD_LDS16(ap, As + wave * 1024 + r * 512);
      int br = n0 + row; if (br >= N) br = N - 1;
      const unsigned short* bp = B + (size_t)br * K + k0 + kq;
      GLOAD_LDS16(bp, Bs + wave * 1024 + r * 512);
    }
    __syncthreads();
    v8s af[4], bfr[4];
#pragma unroll
    for (int i = 0; i < 4; ++i)
      af[i] = *(const v8s*)&As[(wm + i * 16 + lrow) * 32 + lquad * 8];
#pragma unroll
    for (int j = 0; j < 4; ++j)
      bfr[j] = *(const v8s*)&Bs[(wn + j * 16 + lrow) * 32 + lquad * 8];
#pragma unroll
    for (int i = 0; i < 4; ++i)
#pragma unroll
      for (int j = 0; j < 4; ++j)
        acc[i][j] = __builtin_amdgcn_mfma_f32_16x16x32_bf16(af[i], bfr[j], acc[i][j], 0, 0, 0);
  }

#pragma unroll
  for (int i = 0; i < 4; ++i) {
    int grow = m0 + wm + i * 16 + lquad * 4;
#pragma unroll
    for (int j = 0; j < 4; ++j) {
      int gcol = n0 + wn + j * 16 + lrow;
      if (gcol < N) {
#pragma unroll
        for (int r = 0; r < 4; ++r)
          C[(size_t)(grow + r) * N + gcol] = acc[i][j][r];
      }
    }
  }
}

// ---------------- bf16 NT GEMM 64x128 ----------------
__global__ __launch_bounds__(256) void gemm_nt_bf16_64(
    const unsigned short* __restrict__ A, const unsigned short* __restrict__ B,
    float* __restrict__ C, int M, int N, int K)
{
  __shared__ unsigned short As[64 * 32];
  __shared__ unsigned short Bs[128 * 32];
  const int m0 = blockIdx.x * 64;
  const int n0 = blockIdx.y * 128;
  const int tid = threadIdx.x;
  const int wave = tid >> 6, lane = tid & 63;
  const int wm = (wave & 1) * 32, wn = (wave >> 1) * 64;
  const int lrow = lane & 15, lquad = lane >> 4;

  v4f acc[2][4] = {};

  for (int k0 = 0; k0 < K; k0 += 32) {
    __syncthreads();
    {
      int e = wave * 64 + lane;
      int row = e >> 2;
      int kq = (e & 3) * 8;
      const unsigned short* ap = A + (size_t)(m0 + row) * K + k0 + kq;
      GLOAD_LDS16(ap, As + wave * 512);
    }
#pragma unroll
    for (int r = 0; r < 2; ++r) {
      int e = wave * 128 + r * 64 + lane;
      int row = e >> 2;
      int kq = (e & 3) * 8;
      const unsigned short* bp = B + (size_t)(n0 + row) * K + k0 + kq;
      GLOAD_LDS16(bp, Bs + wave * 1024 + r * 512);
    }
    __syncthreads();
    v8s af[2], bfr[4];
#pragma unroll
    for (int i = 0; i < 2; ++i)
      af[i] = *(const v8s*)&As[(wm + i * 16 + lrow) * 32 + lquad * 8];
#pragma unroll
    for (int j = 0; j < 4; ++j)
      bfr[j] = *(const v8s*)&Bs[(wn + j * 16 + lrow) * 32 + lquad * 8];
#pragma unroll
    for (int i = 0; i < 2; ++i)
#pragma unroll
      for (int j = 0; j < 4; ++j)
        acc[i][j] = __builtin_amdgcn_mfma_f32_16x16x32_bf16(af[i], bfr[j], acc[i][j], 0, 0, 0);
  }

#pragma unroll
  for (int i = 0; i < 2; ++i) {
    int grow = m0 + wm + i * 16 + lquad * 4;
#pragma unroll
    for (int j = 0; j < 4; ++j) {
      int gcol = n0 + wn + j * 16 + lrow;
#pragma unroll
      for (int r = 0; r < 4; ++r)
        C[(size_t)(grow + r) * N + gcol] = acc[i][j][r];
    }
  }
}

// ---------------- causal depthwise conv1d(4) + SiLU, LDS-tiled ------------
// tile: 32 l-rows x 128 channels; each zx element read once (+3-row halo)
__global__ __launch_bounds__(256) void conv_silu_kernel(
    const float* __restrict__ zx, const float* __restrict__ cw,
    const float* __restrict__ cb, float* __restrict__ out)
{
  const int l0 = blockIdx.x * 32, c0 = blockIdx.y * 128;
  const int tid = threadIdx.x;
  __shared__ float zs[35][128];
  __shared__ float cwl[4][128];
  __shared__ float cbl[128];
  for (int e = tid; e < 35 * 128; e += 256) {
    int k = e >> 7, cc = e & 127;
    int l = l0 + k - 3;
    zs[k][cc] = (l >= 0) ? zx[(size_t)l * DPROJ + DIN + c0 + cc] : 0.f;
  }
  for (int e = tid; e < 512; e += 256)
    cwl[e & 3][e >> 2] = cw[c0 * 4 + e];
  if (tid < 128) cbl[tid] = cb[c0 + tid];
  __syncthreads();
#pragma unroll
  for (int i = 0; i < 16; ++i) {
    int idx = i * 256 + tid;
    int ll = idx >> 7, cc = idx & 127;
    float acc = cbl[cc];
#pragma unroll
    for (int j = 0; j < 4; ++j)
      acc += zs[ll + j][cc] * cwl[j][cc];
    out[(size_t)(l0 + ll) * CONVD + c0 + cc] = acc / (1.f + __expf(-acc));
  }
}

// ---------------- dt = softplus(raw + bias) ----------------
__global__ void dt_kernel(const float* __restrict__ zx,
                          const float* __restrict__ dtb,
                          float* __restrict__ dt)
{
  int e = blockIdx.x * 256 + threadIdx.x;
  int l = e >> 5, h = e & 31;
  float v = zx[(size_t)l * DPROJ + (DPROJ - NH) + h] + dtb[h];
  dt[e] = (v > 20.f) ? v : log1pf(__expf(v));
}

// ---------------- per-(head,chunk) inclusive cumsum of A*dt ----------------
__global__ void acum_kernel(const float* __restrict__ dt,
                            const float* __restrict__ alog,
                            float* __restrict__ acum)
{
  int h = blockIdx.x & 31, c = blockIdx.x >> 5;
  int t = threadIdx.x;
  int l = c * CKLEN + t;
  float A = -__expf(alog[h]);
  __shared__ float s[256];
  s[t] = A * dt[l * NH + h];
  __syncthreads();
  for (int off = 1; off < 256; off <<= 1) {
    float add = (t >= off) ? s[t - off] : 0.f;
    __syncthreads();
    s[t] += add;
    __syncthreads();
  }
  acum[h * L_SEQ + l] = s[t];
}

// ---------------- prep: Xd (bf16 [c][h][p][t]), Btw (bf16 [c][h][n][t]),
//                  Cbf (bf16 [c][l][n], head-independent) ----------
__global__ __launch_bounds__(256) void prep_kernel(
    const float* __restrict__ xbc, const float* __restrict__ dt,
    const float* __restrict__ acum, unsigned short* __restrict__ Xd,
    unsigned short* __restrict__ Btw, unsigned short* __restrict__ Cbf)
{
  const int h = blockIdx.x & 31, c = blockIdx.x >> 5;
  const int tid = threadIdx.x;
  __shared__ float Ac[256], Dt[256], Wd[256];
  __shared__ float Xs[32][129];
  __shared__ float Bs2[32][65];
  int l = c * CKLEN + tid;
  float a = acum[h * L_SEQ + l];
  Ac[tid] = a;
  Dt[tid] = dt[l * NH + h];
  __syncthreads();
  float alast = Ac[255];
  Wd[tid] = __expf(fminf(alast - a, 0.f));
  __syncthreads();
  unsigned short* XdB = Xd + (size_t)(c * NH + h) * (HD * CKLEN);
  unsigned short* BtB = Btw + (size_t)(c * NH + h) * (NSTATE * CKLEN);
  for (int t0 = 0; t0 < CKLEN; t0 += 32) {
    for (int e = tid; e < 32 * 128; e += 256) {
      int tt = e >> 7, pp = e & 127;
      Xs[tt][pp] = xbc[(size_t)(c * CKLEN + t0 + tt) * CONVD + h * HD + pp];
    }
    for (int e = tid; e < 32 * 64; e += 256) {
      int tt = e >> 6, nn = e & 63;
      Bs2[tt][nn] = xbc[(size_t)(c * CKLEN + t0 + tt) * CONVD + DIN + nn];
    }
    __syncthreads();
    {
      int p = tid >> 1, th = (tid & 1) * 16;
      v8s r0, r1;
#pragma unroll
      for (int k = 0; k < 8; ++k) {
        r0[k] = (short)to_bf16(Xs[th + k][p] * Dt[t0 + th + k]);
        r1[k] = (short)to_bf16(Xs[th + 8 + k][p] * Dt[t0 + th + 8 + k]);
      }
      *(v8s*)&XdB[p * CKLEN + t0 + th] = r0;
      *(v8s*)&XdB[p * CKLEN + t0 + th + 8] = r1;
    }
    {
      int n = tid >> 2, tq = (tid & 3) * 8;
      v8s r;
#pragma unroll
      for (int k = 0; k < 8; ++k)
        r[k] = (short)to_bf16(Bs2[tq + k][n] * Wd[t0 + tq + k]);
      *(v8s*)&BtB[n * CKLEN + t0 + tq] = r;
    }
    __syncthreads();
  }
  if (h == 0) {
    for (int e = tid; e < CKLEN * NSTATE; e += 256) {
      int ll = e >> 6, nn = e & 63;
      Cbf[(size_t)c * (CKLEN * NSTATE) + e] =
          to_bf16(xbc[(size_t)(c * CKLEN + ll) * CONVD + DIN + NSTATE + nn]);
    }
  }
}

// ---------------- G[c][l][s] = C_l . B_s (fp32, per chunk) ----------------
__global__ __launch_bounds__(256) void g_kernel(const float* __restrict__ xbc,
                                                float* __restrict__ G)
{
  int c = blockIdx.z;
  int l0 = blockIdx.y * 64, s0 = blockIdx.x * 64;
  __shared__ float Cs[64][65];
  __shared__ float Bs[64][65];
  int tid = threadIdx.x;
  for (int e = tid; e < 64 * 64; e += 256) {
    int r = e >> 6, k = e & 63;
    Cs[r][k] = xbc[(size_t)(c * CKLEN + l0 + r) * CONVD + DIN + NSTATE + k];
    Bs[r][k] = xbc[(size_t)(c * CKLEN + s0 + r) * CONVD + DIN + k];
  }
  __syncthreads();
  int tx = tid & 15, ty = tid >> 4;
  float acc[4][4] = {};
  for (int k = 0; k < 64; ++k) {
    float a[4], b[4];
#pragma unroll
    for (int i = 0; i < 4; ++i) a[i] = Cs[ty * 4 + i][k];
#pragma unroll
    for (int j = 0; j < 4; ++j) b[j] = Bs[tx * 4 + j][k];
#pragma unroll
    for (int i = 0; i < 4; ++i)
#pragma unroll
      for (int j = 0; j < 4; ++j) acc[i][j] += a[i] * b[j];
  }
  for (int i = 0; i < 4; ++i)
    for (int j = 0; j < 4; ++j)
      G[((size_t)c * CKLEN + l0 + ty * 4 + i) * CKLEN + s0 + tx * 4 + j] = acc[i][j];
}

// ---------------- Gexp v2: G tile in LDS once, loop all 32 heads ----------
// grid: 256 blocks = (c=8) x (l-band=4 of 64) x (s-band=8 of 32)
__global__ __launch_bounds__(256) void gexp_kernel_v2(
    const float* __restrict__ G, const float* __restrict__ acum,
    unsigned short* __restrict__ Gexp)
{
  const int b = blockIdx.x;
  const int si = b & 7, li = (b >> 3) & 3, c = b >> 5;
  const int l0 = li * 64, s0 = si * 32;
  const int tid = threadIdx.x;
  const int r = tid >> 2, sc = (tid & 3) * 8;   // thread -> (row, 8-s chunk)

  if (s0 >= l0 + 64) {   // strictly-upper tile: all zeros
    v8s z = {};
    for (int h = 0; h < NH; ++h)
      *(v8s*)&Gexp[(size_t)(c * NH + h) * 65536 + (size_t)(l0 + r) * 256 + s0 + sc] = z;
    return;
  }

  __shared__ float Gs[64 * 32];
  __shared__ float Acl[32][64];
  __shared__ float Acs[32][32];
  for (int e = tid; e < 2048; e += 256) {
    int rr = e >> 5, cc = e & 31;
    Gs[e] = G[(size_t)c * 65536 + (size_t)(l0 + rr) * 256 + s0 + cc];
  }
  for (int e = tid; e < 2048; e += 256) {
    int hh = e >> 6, rr = e & 63;
    Acl[hh][rr] = acum[hh * L_SEQ + c * CKLEN + l0 + rr];
  }
  for (int e = tid; e < 1024; e += 256) {
    int hh = e >> 5, ss = e & 31;
    Acs[hh][ss] = acum[hh * L_SEQ + c * CKLEN + s0 + ss];
  }
  __syncthreads();

  float g8[8];
#pragma unroll
  for (int k = 0; k < 8; ++k) g8[k] = Gs[r * 32 + sc + k];

  for (int h = 0; h < NH; ++h) {
    float al = Acl[h][r];
    v8s o;
#pragma unroll
    for (int k = 0; k < 8; ++k) {
      int s = s0 + sc + k;
      float m = 0.f;
      if (s <= l0 + r) m = g8[k] * __expf(fminf(al - Acs[h][sc + k], 0.f));
      o[k] = (short)to_bf16(m);
    }
    *(v8s*)&Gexp[(size_t)(c * NH + h) * 65536 + (size_t)(l0 + r) * 256 + s0 + sc] = o;
  }
}

// ---------------- chunk states: st[p][n] = Xd[p][:] . Btw[n][:] -----------
__global__ __launch_bounds__(256) void states_kernel_v2(
    const unsigned short* __restrict__ Xd, const unsigned short* __restrict__ Btw,
    float* __restrict__ st)
{
  const int h = blockIdx.x & 31, c = blockIdx.x >> 5;
  const int tid = threadIdx.x;
  const int wave = tid >> 6, lane = tid & 63;
  const int wm = (wave & 1) * 64, wn = (wave >> 1) * 32;
  const int lrow = lane & 15, lquad = lane >> 4;

  __shared__ unsigned short As[128 * 32];
  __shared__ unsigned short Bs[64 * 32];
  const unsigned short* Ab = Xd + (size_t)(c * NH + h) * (HD * CKLEN);
  const unsigned short* Bb = Btw + (size_t)(c * NH + h) * (NSTATE * CKLEN);

  v4f acc[4][2] = {};

  for (int k0 = 0; k0 < CKLEN; k0 += 32) {
    __syncthreads();
#pragma unroll
    for (int r = 0; r < 2; ++r) {
      int e = wave * 128 + r * 64 + lane;
      int row = e >> 2, kq = (e & 3) * 8;
      GLOAD_LDS16(Ab + (size_t)row * CKLEN + k0 + kq, As + wave * 1024 + r * 512);
    }
    {
      int e = wave * 64 + lane;
      int row = e >> 2, kq = (e & 3) * 8;
      GLOAD_LDS16(Bb + (size_t)row * CKLEN + k0 + kq, Bs + wave * 512);
    }
    __syncthreads();
    v8s af[4], bfr[2];
#pragma unroll
    for (int i = 0; i < 4; ++i)
      af[i] = *(const v8s*)&As[(wm + i * 16 + lrow) * 32 + lquad * 8];
#pragma unroll
    for (int j = 0; j < 2; ++j)
      bfr[j] = *(const v8s*)&Bs[(wn + j * 16 + lrow) * 32 + lquad * 8];
#pragma unroll
    for (int i = 0; i < 4; ++i)
#pragma unroll
      for (int j = 0; j < 2; ++j)
        acc[i][j] = __builtin_amdgcn_mfma_f32_16x16x32_bf16(af[i], bfr[j], acc[i][j], 0, 0, 0);
  }

  float* outp = st + (size_t)(c * NH + h) * (HD * NSTATE);
#pragma unroll
  for (int i = 0; i < 4; ++i) {
    int p0 = wm + i * 16 + lquad * 4;
#pragma unroll
    for (int j = 0; j < 2; ++j) {
      int n = wn + j * 16 + lrow;
#pragma unroll
      for (int r = 0; r < 4; ++r)
        outp[(size_t)(p0 + r) * NSTATE + n] = acc[i][j][r];
    }
  }
}

// ---------------- inter-chunk scan -> bf16 sp ----------------
__global__ void scan_kernel(const float* __restrict__ acum,
                            const float* __restrict__ st,
                            unsigned short* __restrict__ spbf)
{
  int e = blockIdx.x * 256 + threadIdx.x;   // over NH*HD*NSTATE = 262144
  int h = e >> 13;
  float running = 0.f;
#pragma unroll
  for (int c = 0; c < NCHUNK; ++c) {
    spbf[(size_t)c * 262144 + e] = to_bf16(running);
    float dec = __expf(fminf(acum[h * L_SEQ + c * CKLEN + 255], 0.f));
    running = running * dec + st[(size_t)c * 262144 + e];
  }
}

// ---------------- Y: acc = Cbf @ sp^T; acc *= exp(Ac[l]); acc += Gexp @ Xd^T;
//                  Y = acc + D*xs ----------------
__global__ __launch_bounds__(256) void y_kernel_v2(
    const unsigned short* __restrict__ Gexp, const unsigned short* __restrict__ Xd,
    const unsigned short* __restrict__ Cbf, const unsigned short* __restrict__ spbf,
    const float* __restrict__ xbc, const float* __restrict__ acum,
    const float* __restrict__ Dp, float* __restrict__ Y)
{
  const int b = blockIdx.x, h = blockIdx.y, c = blockIdx.z;
  const int tid = threadIdx.x;
  const int wave = tid >> 6, lane = tid & 63;
  const int wm = wave * 32;
  const int lrow = lane & 15, lquad = lane >> 4;

  __shared__ unsigned short As[128 * 32];
  __shared__ unsigned short Bs[128 * 32];

  v4f acc[2][8] = {};

  // ---- state part first: acc = Cbf @ sp^T ----
  const unsigned short* Ca = Cbf + (size_t)c * (CKLEN * NSTATE) + (size_t)b * 128 * NSTATE;
  const unsigned short* Sb = spbf + (size_t)(c * NH + h) * (HD * NSTATE);
  for (int n0 = 0; n0 < NSTATE; n0 += 32) {
    __syncthreads();
#pragma unroll
    for (int r = 0; r < 2; ++r) {
      int e = wave * 128 + r * 64 + lane;
      int row = e >> 2, kq = (e & 3) * 8;
      GLOAD_LDS16(Ca + (size_t)row * NSTATE + n0 + kq, As + wave * 1024 + r * 512);
      GLOAD_LDS16(Sb + (size_t)row * NSTATE + n0 + kq, Bs + wave * 1024 + r * 512);
    }
    __syncthreads();
    v8s af[2], bfr[8];
#pragma unroll
    for (int i = 0; i < 2; ++i)
      af[i] = *(const v8s*)&As[(wm + i * 16 + lrow) * 32 + lquad * 8];
#pragma unroll
    for (int j = 0; j < 8; ++j)
      bfr[j] = *(const v8s*)&Bs[(j * 16 + lrow) * 32 + lquad * 8];
#pragma unroll
    for (int i = 0; i < 2; ++i)
#pragma unroll
      for (int j = 0; j < 8; ++j)
        acc[i][j] = __builtin_amdgcn_mfma_f32_16x16x32_bf16(af[i], bfr[j], acc[i][j], 0, 0, 0);
  }

  // ---- row-scale by per-head decay exp(Ac[l]) (fp32) ----
#pragma unroll
  for (int i = 0; i < 2; ++i) {
#pragma unroll
    for (int r = 0; r < 4; ++r) {
      int Lg = c * CKLEN + b * 128 + wm + i * 16 + lquad * 4 + r;
      float eA = __expf(fminf(acum[h * L_SEQ + Lg], 0.f));
#pragma unroll
      for (int j = 0; j < 8; ++j) acc[i][j][r] *= eA;
    }
  }

  // ---- diagonal part: acc += Gexp @ Xd^T ----
  const unsigned short* Ga = Gexp + (size_t)(c * NH + h) * (CKLEN * CKLEN)
                           + (size_t)b * 128 * CKLEN;
  const unsigned short* Xb = Xd + (size_t)(c * NH + h) * (HD * CKLEN);

  const int smax = (b + 1) * 128;
  for (int s0 = 0; s0 < smax; s0 += 32) {
    __syncthreads();
#pragma unroll
    for (int r = 0; r < 2; ++r) {
      int e = wave * 128 + r * 64 + lane;
      int row = e >> 2, kq = (e & 3) * 8;
      GLOAD_LDS16(Ga + (size_t)row * CKLEN + s0 + kq, As + wave * 1024 + r * 512);
      GLOAD_LDS16(Xb + (size_t)row * CKLEN + s0 + kq, Bs + wave * 1024 + r * 512);
    }
    __syncthreads();
    if (s0 <= b * 128 + wm + 31) {    // causal wave skip
      v8s af[2], bfr[8];
#pragma unroll
      for (int i = 0; i < 2; ++i)
        af[i] = *(const v8s*)&As[(wm + i * 16 + lrow) * 32 + lquad * 8];
#pragma unroll
      for (int j = 0; j < 8; ++j)
        bfr[j] = *(const v8s*)&Bs[(j * 16 + lrow) * 32 + lquad * 8];
#pragma unroll
      for (int i = 0; i < 2; ++i)
#pragma unroll
        for (int j = 0; j < 8; ++j)
          acc[i][j] = __builtin_amdgcn_mfma_f32_16x16x32_bf16(af[i], bfr[j], acc[i][j], 0, 0, 0);
    }
  }

  const float Dh = Dp[h];
#pragma unroll
  for (int i = 0; i < 2; ++i) {
#pragma unroll
    for (int j = 0; j < 8; ++j) {
      int p = j * 16 + lrow;
#pragma unroll
      for (int r = 0; r < 4; ++r) {
        int Lg = c * CKLEN + b * 128 + wm + i * 16 + lquad * 4 + r;
        float xs = xbc[(size_t)Lg * CONVD + h * HD + p];
        Y[(size_t)Lg * DIN + h * HD + p] = acc[i][j][r] + Dh * xs;
      }
    }
  }
}

// ---------------- gated RMSNorm -> bf16 ----------------
__global__ __launch_bounds__(256) void norm_gate_kernel(const float* __restrict__ Y,
                                                        const float* __restrict__ zx,
                                                        const float* __restrict__ nw,
                                                        unsigned short* __restrict__ gbf)
{
  int l = blockIdx.x;
  int t = threadIdx.x;
  float g[16];
  float ss = 0.f;
#pragma unroll
  for (int i = 0; i < 16; ++i) {
    int idx = i * 256 + t;
    float z = zx[(size_t)l * DPROJ + idx];
    float y = Y[(size_t)l * DIN + idx];
    float gv = y * (z / (1.f + __expf(-z)));
    g[i] = gv;
    ss += gv * gv;
  }
#pragma unroll
  for (int off = 32; off > 0; off >>= 1) ss += __shfl_down(ss, off);
  __shared__ float red[4];
  if ((t & 63) == 0) red[t >> 6] = ss;
  __syncthreads();
  float total = red[0] + red[1] + red[2] + red[3];
  float scale = rsqrtf(total / (float)DIN + 1e-5f);
#pragma unroll
  for (int i = 0; i < 16; ++i) {
    int idx = i * 256 + t;
    gbf[(size_t)l * DIN + idx] = to_bf16(g[i] * scale * nw[idx]);
  }
}

// ---------------- launch ----------------
extern "C" void kernel_launch(void* const* d_in, const int* in_sizes, int n_in,
                              void* d_out, int out_size, void* d_ws, size_t ws_size,
                              hipStream_t stream) {
  const float* x    = (const float*)d_in[0];
  const float* w1   = (const float*)d_in[1];
  const float* cw   = (const float*)d_in[2];
  const float* cb   = (const float*)d_in[3];
  const float* dtb  = (const float*)d_in[4];
  const float* alog = (const float*)d_in[5];
  const float* Dp   = (const float*)d_in[6];
  const float* nw   = (const float*)d_in[7];
  const float* w2   = (const float*)d_in[8];
  float* out = (float*)d_out;
  float* ws  = (float*)d_ws;

  // scratch layout (float units). Gexp/Btw overlay xbf/w1bf (dead after gemm1).
  unsigned short* xbf  = (unsigned short*)(ws + 0);          // 2048*2048 bf16
  unsigned short* w1bf = (unsigned short*)(ws + 2097152);    // 8352*2048 bf16
  unsigned short* Gexp = (unsigned short*)(ws + 0);          // 8*32*256*256 bf16 (post-gemm1)
  unsigned short* Btw  = (unsigned short*)(ws + 8388608);    // 8*32*64*256 bf16 (post-gemm1)
  unsigned short* w2bf = (unsigned short*)(ws + 10649600);   // 2048*4096 bf16
  float* zx   = ws + 14843904;   // 2048*8352
  float* xbc  = ws + 31948800;   // 2048*4224
  float* dt   = ws + 40599552;   // 2048*32
  float* acum = ws + 40665088;   // 32*2048
  float* G    = ws + 40730624;   // 8*256*256 fp32
  float* st   = ws + 41254912;   // 8*32*128*64 fp32
  float* Y    = ws + 43352064;   // 2048*4096
  unsigned short* gbf  = (unsigned short*)(ws + 51740672);   // 2048*4096 bf16
  unsigned short* Xd   = (unsigned short*)(ws + 53837824);   // 8*32*128*256 bf16
  unsigned short* Cbf  = (unsigned short*)(ws + 58032128);   // 8*256*64 bf16
  unsigned short* spbf = (unsigned short*)(ws + 58097664);   // 8*32*128*64 bf16

  cvt_bf16_kernel<<<4194304 / 2048, 256, 0, stream>>>(x, xbf, 4194304);
  cvt_bf16_kernel<<<17104896 / 2048, 256, 0, stream>>>(w1, w1bf, 17104896);
  cvt_bf16_kernel<<<8388608 / 2048, 256, 0, stream>>>(w2, w2bf, 8388608);

  // zxbcdt = x @ in_proj_w^T   (M=2048, N=8352, K=2048)
  gemm_nt_bf16<<<dim3(16, 66), 256, 0, stream>>>(xbf, w1bf, zx, 2048, 8352, 2048);

  conv_silu_kernel<<<dim3(64, 33), 256, 0, stream>>>(zx, cw, cb, xbc);
  dt_kernel<<<(L_SEQ * NH) / 256, 256, 0, stream>>>(zx, dtb, dt);
  acum_kernel<<<NCHUNK * NH, 256, 0, stream>>>(dt, alog, acum);

  prep_kernel<<<NCHUNK * NH, 256, 0, stream>>>(xbc, dt, acum, Xd, Btw, Cbf);
  g_kernel<<<dim3(4, 4, NCHUNK), 256, 0, stream>>>(xbc, G);
  gexp_kernel_v2<<<256, 256, 0, stream>>>(G, acum, Gexp);

  states_kernel_v2<<<NCHUNK * NH, 256, 0, stream>>>(Xd, Btw, st);
  scan_kernel<<<262144 / 256, 256, 0, stream>>>(acum, st, spbf);
  y_kernel_v2<<<dim3(2, NH, NCHUNK), 256, 0, stream>>>(Gexp, Xd, Cbf, spbf, xbc, acum, Dp, Y);

  norm_gate_kernel<<<L_SEQ, 256, 0, stream>>>(Y, zx, nw, gbf);

  // out = g @ out_proj_w^T   (M=2048, N=2048, K=4096)
  gemm_nt_bf16_64<<<dim3(32, 16), 256, 0, stream>>>(gbf, w2bf, out, 2048, 2048, 4096);
}